// Round 15
// baseline (510.471 us; speedup 1.0000x reference)
//
#include <hip/hip_runtime.h>
#include <cstdint>

// ---------- types ----------
typedef __bf16 bf16;
typedef __bf16 bf16x8 __attribute__((ext_vector_type(8)));
typedef float  f32x4  __attribute__((ext_vector_type(4)));
typedef float  f32x16 __attribute__((ext_vector_type(16)));

#define AS1(p) ((__attribute__((address_space(1))) void*)(p))
#define AS3(p) ((__attribute__((address_space(3))) void*)(p))

__device__ __forceinline__ void gload16(const void* g, void* l) {
  __builtin_amdgcn_global_load_lds(AS1(g), AS3(l), 16, 0, 0);
}

// ---------- problem constants ----------
constexpr int B_ = 2, S_ = 2048, E_ = 4096, H_ = 32, KVH_ = 8, D_ = 128;
constexpr int QPK_ = H_ / KVH_;            // 4
constexpr int F_ = E_ + 2 * KVH_ * D_;     // 6144
constexpr int M_ = B_ * S_;                // 4096 rows of x

// ---------- merged init: x->bf16, wqkv->bf16, rope table (one launch) ----------
__device__ __forceinline__ void conv8(const float* in, bf16* out, int i) {
  const float4* p = (const float4*)(in + (size_t)i * 8);
  float4 a = p[0], b = p[1];
  bf16x8 o;
  o[0] = (bf16)a.x; o[1] = (bf16)a.y; o[2] = (bf16)a.z; o[3] = (bf16)a.w;
  o[4] = (bf16)b.x; o[5] = (bf16)b.y; o[6] = (bf16)b.z; o[7] = (bf16)b.w;
  *(bf16x8*)(out + (size_t)i * 8) = o;
}

__global__ void init_k(const float* __restrict__ x, bf16* __restrict__ xbf,
                       const float* __restrict__ wqkv, bf16* __restrict__ wqkvbf,
                       float2* __restrict__ tab) {
  int i = blockIdx.x * 256 + threadIdx.x;
  if (i < 2097152) {                       // x: 16M elems
    conv8(x, xbf, i);
  } else if (i < 2097152 + 3145728) {      // wqkv: 25.2M elems
    conv8(wqkv, wqkvbf, i - 2097152);
  } else {                                 // rope table: S*64
    int j = i - 5242880;
    if (j < 131072) {
      int s = j >> 6, f = j & 63;
      float inv = powf(10000.0f, -2.0f * (float)f / 128.0f);
      float ang = (float)s * inv;
      tab[j] = make_float2(cosf(ang), sinf(ang));
    }
  }
}

// ---------- fp32 -> bf16 convert (wo only) ----------
__global__ void f2bf_k(const float* __restrict__ in, bf16* __restrict__ out, int n8) {
  int i = blockIdx.x * 256 + threadIdx.x;
  if (i >= n8) return;
  conv8(in, out, i);
}

// ============ 256x192 2-phase GEMM with 32x32x16 MFMA (GEMM1) ============
// r14->r15: 32x32x16 bf16 MFMA is 20% cheaper per FLOP on the matrix pipe
// (m119: 4060 vs 3378 FLOP/cyc) and halves instruction count. 8 waves as
// 4M x 2N; per-wave 64x96 = acc[2][3] f32x16. A/B operand: row=lane&31,
// k=(lane>>5)*8+e; C/D: col=lane&31, row=(reg&3)+8*(reg>>2)+4*(lane>>5)
// [measured m74/m101]. Staging/swizzle/boundary identical to r13 gemm192
// (512 blocks = 2 exact rounds; B tri-buf; counted vmcnt(3)).
template <typename OutT>
__global__ __launch_bounds__(512, 2)
void gemm192(const bf16* __restrict__ A, const bf16* __restrict__ B,
             OutT* __restrict__ C, int M, int N, int K) {
  __shared__ bf16 As[2][256 * 64];   // 32KB each
  __shared__ bf16 Bs[3][192 * 64];   // 24KB each
  const int tid = threadIdx.x;
  const int wid = tid >> 6, lane = tid & 63;
  const int l31 = lane & 31, hi = lane >> 5;
  const int wr = wid >> 1, wc = wid & 1;      // 4M x 2N waves
  const int bm = blockIdx.x, bn = blockIdx.y;
  const bf16* Ab = A + (size_t)bm * 256 * K;
  const bf16* Bb = B + (size_t)bn * 192 * K;
  const int nT = K >> 6;
  const int swzr = (l31 & 7) << 4;   // read-side byte swizzle (row&7 = l31&7)

  f32x16 acc[2][3];
#pragma unroll
  for (int mb = 0; mb < 2; ++mb)
#pragma unroll
    for (int n = 0; n < 3; ++n)
#pragma unroll
      for (int r = 0; r < 16; ++r) acc[mb][n][r] = 0.f;

  auto stgA = [&](int t) {   // 256x64 tile, 32KB, 4 loads/thread
    bf16* dst = &As[t & 1][0];
#pragma unroll
    for (int i = 0; i < 4; ++i) {
      int lb = i * 8192 + wid * 1024 + lane * 16;
      int row = lb >> 7;
      int colb = (lb & 127) ^ ((row & 7) << 4);
      gload16(Ab + (size_t)row * K + t * 64 + (colb >> 1),
              dst + ((i * 8192 + wid * 1024) >> 1));
    }
  };
  auto stgB = [&](int t) {   // 192x64 tile, 24KB, 3 loads/thread
    bf16* dst = &Bs[t % 3][0];
#pragma unroll
    for (int i = 0; i < 3; ++i) {
      int lb = i * 8192 + wid * 1024 + lane * 16;
      int row = lb >> 7;
      int colb = (lb & 127) ^ ((row & 7) << 4);
      gload16(Bb + (size_t)row * K + t * 64 + (colb >> 1),
              dst + ((i * 8192 + wid * 1024) >> 1));
    }
  };

  // ---- prologue: A0+B0 staged, B1 issued; vmcnt(3) keeps B1 in flight ----
  stgA(0); stgB(0);
  if (nT > 1) { stgB(1); asm volatile("s_waitcnt vmcnt(3)"); }
  else        { asm volatile("s_waitcnt vmcnt(0)"); }
  __builtin_amdgcn_sched_barrier(0);
  __builtin_amdgcn_s_barrier();

  bf16x8 af[4], bfr[3][4];
  for (int t = 0; t < nT; ++t) {
    const bf16* Asc = &As[t & 1][0];
    const bf16* Bsc = &Bs[t % 3][0];
    // ---- P1: A mb=0 frags (4 reads) + ALL B (12 reads); stage A(t+1) ----
#pragma unroll
    for (int ks = 0; ks < 4; ++ks) {
      int arow = wr * 64 + l31;
      af[ks] = *(const bf16x8*)&Asc[(arow << 6) + (((ks * 32 + hi * 16) ^ swzr) >> 1)];
    }
#pragma unroll
    for (int n = 0; n < 3; ++n) {
      int brow = wc * 96 + n * 32 + l31;
#pragma unroll
      for (int ks = 0; ks < 4; ++ks)
        bfr[n][ks] = *(const bf16x8*)&Bsc[(brow << 6) + (((ks * 32 + hi * 16) ^ swzr) >> 1)];
    }
    if (t + 1 < nT) stgA(t + 1);
    __builtin_amdgcn_s_barrier();
    asm volatile("s_waitcnt lgkmcnt(0)");
    __builtin_amdgcn_sched_barrier(0);
    __builtin_amdgcn_s_setprio(1);
#pragma unroll
    for (int ks = 0; ks < 4; ++ks)
#pragma unroll
      for (int n = 0; n < 3; ++n)
        acc[0][n] = __builtin_amdgcn_mfma_f32_32x32x16_bf16(af[ks], bfr[n][ks], acc[0][n], 0, 0, 0);
    __builtin_amdgcn_s_setprio(0);
    __builtin_amdgcn_s_barrier();
    // ---- P2: A mb=1 frags (4 reads); stage B(t+2); counted boundary vmcnt --
#pragma unroll
    for (int ks = 0; ks < 4; ++ks) {
      int arow = wr * 64 + 32 + l31;
      af[ks] = *(const bf16x8*)&Asc[(arow << 6) + (((ks * 32 + hi * 16) ^ swzr) >> 1)];
    }
    if (t + 2 < nT) stgB(t + 2);
    __builtin_amdgcn_s_barrier();
    asm volatile("s_waitcnt lgkmcnt(0)");
    __builtin_amdgcn_sched_barrier(0);
    __builtin_amdgcn_s_setprio(1);
#pragma unroll
    for (int ks = 0; ks < 4; ++ks)
#pragma unroll
      for (int n = 0; n < 3; ++n)
        acc[1][n] = __builtin_amdgcn_mfma_f32_32x32x16_bf16(af[ks], bfr[n][ks], acc[1][n], 0, 0, 0);
    __builtin_amdgcn_s_setprio(0);
    if (t + 2 < nT)      { asm volatile("s_waitcnt vmcnt(3)"); }
    else if (t + 1 < nT) { asm volatile("s_waitcnt vmcnt(0)"); }
    __builtin_amdgcn_sched_barrier(0);
    __builtin_amdgcn_s_barrier();
  }

  // epilogue: 32x32 C/D layout col=lane&31, row=(reg&3)+8*(reg>>2)+4*(lane>>5)
#pragma unroll
  for (int mb = 0; mb < 2; ++mb)
#pragma unroll
    for (int n = 0; n < 3; ++n) {
      f32x16 v = acc[mb][n];
      int col = bn * 192 + wc * 96 + n * 32 + l31;
#pragma unroll
      for (int r = 0; r < 16; ++r) {
        int row = bm * 256 + wr * 64 + mb * 32 + (r & 3) + 8 * (r >> 2) + 4 * hi;
        C[(size_t)row * N + col] = (OutT)v[r];
      }
    }
}

// ============ 256x256 4-phase bf16 GEMM, pair-unrolled (GEMM3, r7 proven) =====
template <typename OutT>
__global__ __launch_bounds__(512, 2)
void gemm256(const bf16* __restrict__ A, const bf16* __restrict__ B,
             OutT* __restrict__ C, int M, int N, int K) {
  __shared__ bf16 As[2][16384];
  __shared__ bf16 Bs[2][16384];
  const int tid = threadIdx.x;
  const int wid = tid >> 6, lane = tid & 63;
  const int l15 = lane & 15, g = lane >> 4;
  const int wr = wid >> 2, wc = wid & 3;
  const int bm = blockIdx.x, bn = blockIdx.y;
  const bf16* Ab = A + (size_t)bm * 256 * K;
  const bf16* Bb = B + (size_t)bn * 256 * K;
  const int nT = K >> 6;
  const int swzr = (l15 & 7) << 4;

  f32x4 acc[8][4];
#pragma unroll
  for (int m = 0; m < 8; ++m)
#pragma unroll
    for (int n = 0; n < 4; ++n) acc[m][n] = (f32x4){0.f, 0.f, 0.f, 0.f};

  auto stg = [&](const bf16* src, bf16* dst, int t, int h) {
#pragma unroll
    for (int i = 0; i < 2; ++i) {
      int lb = h * 16384 + i * 8192 + wid * 1024 + lane * 16;
      int row = lb >> 7;
      int colb = (lb & 127) ^ ((row & 7) << 4);
      gload16(src + (size_t)row * K + t * 64 + (colb >> 1),
              dst + ((h * 16384 + i * 8192 + wid * 1024) >> 1));
    }
  };

  bf16x8 af[4][2];
  bf16x8 bfr[2][2][2];

  stg(Bb, Bs[0], 0, 0); stg(Bb, Bs[0], 0, 1);
  stg(Ab, As[0], 0, 0); stg(Ab, As[0], 0, 1);
  if (nT > 1) {
    stg(Bb, Bs[1], 1, 0); stg(Bb, Bs[1], 1, 1);
    asm volatile("s_waitcnt vmcnt(4)");
  } else {
    asm volatile("s_waitcnt vmcnt(0)");
  }
  __builtin_amdgcn_sched_barrier(0);
  __builtin_amdgcn_s_barrier();

  auto tileK = [&](int t, const int cur) {
    // P1
#pragma unroll
    for (int m = 0; m < 4; ++m) {
      int arow = wr * 128 + m * 16 + l15;
#pragma unroll
      for (int ks = 0; ks < 2; ++ks)
        af[m][ks] = *(const bf16x8*)&As[cur][(arow << 6) + (((ks * 64 + g * 16) ^ swzr) >> 1)];
    }
#pragma unroll
    for (int n = 0; n < 2; ++n) {
      int brow = wc * 64 + n * 16 + l15;
#pragma unroll
      for (int ks = 0; ks < 2; ++ks)
        bfr[0][n][ks] = *(const bf16x8*)&Bs[cur][(brow << 6) + (((ks * 64 + g * 16) ^ swzr) >> 1)];
    }
    if (t + 1 < nT) stg(Ab, As[cur ^ 1], t + 1, 0);
    __builtin_amdgcn_s_barrier();
    asm volatile("s_waitcnt lgkmcnt(0)");
    __builtin_amdgcn_s_setprio(1);
#pragma unroll
    for (int ks = 0; ks < 2; ++ks)
#pragma unroll
      for (int m = 0; m < 4; ++m)
#pragma unroll
        for (int n = 0; n < 2; ++n)
          acc[m][n] = __builtin_amdgcn_mfma_f32_16x16x32_bf16(af[m][ks], bfr[0][n][ks], acc[m][n], 0, 0, 0);
    __builtin_amdgcn_s_setprio(0);
    __builtin_amdgcn_s_barrier();
    // P2
#pragma unroll
    for (int n = 0; n < 2; ++n) {
      int brow = wc * 64 + 32 + n * 16 + l15;
#pragma unroll
      for (int ks = 0; ks < 2; ++ks)
        bfr[1][n][ks] = *(const bf16x8*)&Bs[cur][(brow << 6) + (((ks * 64 + g * 16) ^ swzr) >> 1)];
    }
    if (t + 1 < nT) stg(Ab, As[cur ^ 1], t + 1, 1);
    __builtin_amdgcn_s_barrier();
    asm volatile("s_waitcnt lgkmcnt(0)");
    __builtin_amdgcn_s_setprio(1);
#pragma unroll
    for (int ks = 0; ks < 2; ++ks)
#pragma unroll
      for (int m = 0; m < 4; ++m)
#pragma unroll
        for (int n = 0; n < 2; ++n)
          acc[m][2 + n] = __builtin_amdgcn_mfma_f32_16x16x32_bf16(af[m][ks], bfr[1][n][ks], acc[m][2 + n], 0, 0, 0);
    __builtin_amdgcn_s_setprio(0);
    __builtin_amdgcn_s_barrier();
    // P3
#pragma unroll
    for (int m = 0; m < 4; ++m) {
      int arow = wr * 128 + 64 + m * 16 + l15;
#pragma unroll
      for (int ks = 0; ks < 2; ++ks)
        af[m][ks] = *(const bf16x8*)&As[cur][(arow << 6) + (((ks * 64 + g * 16) ^ swzr) >> 1)];
    }
    if (t + 2 < nT) stg(Bb, Bs[cur], t + 2, 0);
    __builtin_amdgcn_s_barrier();
    asm volatile("s_waitcnt lgkmcnt(0)");
    __builtin_amdgcn_s_setprio(1);
#pragma unroll
    for (int ks = 0; ks < 2; ++ks)
#pragma unroll
      for (int m = 0; m < 4; ++m)
#pragma unroll
        for (int n = 0; n < 2; ++n)
          acc[4 + m][n] = __builtin_amdgcn_mfma_f32_16x16x32_bf16(af[m][ks], bfr[0][n][ks], acc[4 + m][n], 0, 0, 0);
    __builtin_amdgcn_s_setprio(0);
    __builtin_amdgcn_s_barrier();
    // P4
    if (t + 2 < nT) stg(Bb, Bs[cur], t + 2, 1);
    __builtin_amdgcn_s_setprio(1);
#pragma unroll
    for (int ks = 0; ks < 2; ++ks)
#pragma unroll
      for (int m = 0; m < 4; ++m)
#pragma unroll
        for (int n = 0; n < 2; ++n)
          acc[4 + m][2 + n] = __builtin_amdgcn_mfma_f32_16x16x32_bf16(af[m][ks], bfr[1][n][ks], acc[4 + m][2 + n], 0, 0, 0);
    __builtin_amdgcn_s_setprio(0);
    if (t + 2 < nT)      { asm volatile("s_waitcnt vmcnt(4)"); }
    else if (t + 1 < nT) { asm volatile("s_waitcnt vmcnt(0)"); }
    __builtin_amdgcn_sched_barrier(0);
    __builtin_amdgcn_s_barrier();
  };

  for (int tt = 0; tt < nT; tt += 2) {
    tileK(tt, 0);
    tileK(tt + 1, 1);
  }

#pragma unroll
  for (int mh = 0; mh < 2; ++mh)
#pragma unroll
    for (int m = 0; m < 4; ++m) {
      int row0 = bm * 256 + wr * 128 + mh * 64 + m * 16 + g * 4;
#pragma unroll
      for (int nh = 0; nh < 2; ++nh)
#pragma unroll
        for (int n = 0; n < 2; ++n) {
          int col = bn * 256 + wc * 64 + nh * 32 + n * 16 + l15;
          f32x4 v = acc[mh * 4 + m][nh * 2 + n];
#pragma unroll
          for (int r = 0; r < 4; ++r)
            C[(size_t)(row0 + r) * N + col] = (OutT)v[r];
        }
    }
}

// ---------- RoPE on K: qkv -> k[B][KVH][S][D] ----------
__global__ void rope_k_k(const bf16* __restrict__ qkv, const float2* __restrict__ tab,
                         bf16* __restrict__ kout) {
  int idx = blockIdx.x * 256 + threadIdx.x;  // B*S*KVH*16 = 524288
  int c = idx & 15;
  int kvh = (idx >> 4) & 7;
  int s = (idx >> 7) & 2047;
  int b = idx >> 18;
  int d0 = c * 8;
  const bf16* src = qkv + (size_t)(b * 2048 + s) * F_ + kvh * (QPK_ + 2) * D_ + QPK_ * D_ + d0;
  bf16x8 v = *(const bf16x8*)src;
  const float2* tb = tab + s * 64 + (d0 >> 1);
  bf16x8 o;
#pragma unroll
  for (int p = 0; p < 4; ++p) {
    float x0 = (float)v[2 * p], x1 = (float)v[2 * p + 1];
    float2 cs = tb[p];
    o[2 * p]     = (bf16)(x0 * cs.x - x1 * cs.y);
    o[2 * p + 1] = (bf16)(x0 * cs.y + x1 * cs.x);
  }
  *(bf16x8*)(kout + ((size_t)(b * 8 + kvh) * 2048 + s) * 128 + d0) = o;
}

// ---------- V transpose: qkv -> vt[B][KVH][D][S] (LDS tiled 64s x 32d) ----------
__global__ void vtrans_k(const bf16* __restrict__ qkv, bf16* __restrict__ vt) {
  int bidx = blockIdx.x;  // B*KVH*4*32 = 2048
  int st = bidx & 31;
  int dt = (bidx >> 5) & 3;
  int kvh = (bidx >> 7) & 7;
  int b = bidx >> 10;
  __shared__ bf16 tile[64][40];
  int t = threadIdx.x;
  {
    int sl = t >> 2, d0 = (t & 3) * 8;
    bf16x8 v = *(const bf16x8*)(qkv + (size_t)(b * 2048 + st * 64 + sl) * F_ +
                                kvh * (QPK_ + 2) * D_ + (QPK_ + 1) * D_ + dt * 32 + d0);
#pragma unroll
    for (int i = 0; i < 8; ++i) tile[sl][d0 + i] = v[i];
  }
  __syncthreads();
  {
    int dl = t >> 3, s0 = (t & 7) * 8;
    bf16x8 o;
#pragma unroll
    for (int i = 0; i < 8; ++i) o[i] = tile[s0 + i][dl];
    *(bf16x8*)(vt + ((size_t)(b * 8 + kvh) * 128 + dt * 32 + dl) * 2048 + st * 64 + s0) = o;
  }
}

// ---------- causal GQA flash attention (r14 structure + fused Q-RoPE) ----
// r15: Q is read DIRECTLY from qkv with RoPE applied in-register at aq-load
// time (pairs are adjacent d-elements = lane-local; once per q-tile). Kills
// rope_q_k and the qbuf round-trip. wo-convert relocated to the freed region.
__global__ __launch_bounds__(512, 4)
void attn_k(const bf16* __restrict__ qkv, const bf16* __restrict__ k,
            const bf16* __restrict__ vt, const float2* __restrict__ tab,
            bf16* __restrict__ ctx) {
  int bid = blockIdx.x;
  bid = (bid & 7) * 64 + (bid >> 3);   // XCD chunk: each XCD gets 2 (b,kvh) KV sets
  int qp = bid & 7;
  int h = (bid >> 3) & 31;
  int b = bid >> 8;
  int kvh = h >> 2, j = h & 3;
  int tid = threadIdx.x, w = tid >> 6, lane = tid & 63;
  int l15 = lane & 15, g = lane >> 4;

  __shared__ bf16 Ks[2][64 * 128];   // 32KB
  __shared__ bf16 Vs[2][128 * 64];   // 32KB
  __shared__ bf16 Plds[8][16 * 64];  // 16KB, XOR-swizzled rows (128B)

  bf16* Pw = &Plds[w][0];
  const float C2 = 0.08838834764831845f * 1.4426950408889634f;  // scale * log2(e)
  const float NEG = -3.0e38f;

  const bf16* kb_base = k + (size_t)(b * 8 + kvh) * 2048 * 128;
  const bf16* vt_base = vt + (size_t)(b * 8 + kvh) * 128 * 2048;

  auto stage = [&](int kv0, int buf) {
#pragma unroll
    for (int i = 0; i < 2; ++i) {
      int lt = i * 8192 + tid * 16;
      int row = lt >> 8;
      int ch = (lt >> 4) & 15;
      int srcel = (ch ^ (row & 7)) << 3;
      gload16(kb_base + (size_t)(kv0 + row) * 128 + srcel,
              &Ks[buf][(i * 8192 + w * 1024) >> 1]);
    }
#pragma unroll
    for (int i = 0; i < 2; ++i) {
      int lt = i * 8192 + tid * 16;
      int row = lt >> 7;
      int ch = (lt >> 4) & 7;
      int srcel = (ch ^ (row & 7)) << 3;
      gload16(vt_base + (size_t)row * 2048 + kv0 + srcel,
              &Vs[buf][(i * 8192 + w * 1024) >> 1]);
    }
  };

  const int kxor = (l15 & 7) << 4;   // read-side byte swizzle (row = *+l15)

  for (int pass = 0; pass < 2; ++pass) {
    int qt = pass ? (15 - qp) : qp;
    int qrow0 = qt * 128 + w * 16;

    // Q fragments: read from qkv + apply RoPE in-register (lane-local pairs)
    bf16x8 aq[4];
    {
      int s = qrow0 + l15;
      const bf16* qsrc = qkv + (size_t)(b * 2048 + s) * F_ + kvh * (QPK_ + 2) * D_ + j * D_;
      const float2* tb = tab + s * 64;
#pragma unroll
      for (int ks = 0; ks < 4; ++ks) {
        int d0 = ks * 32 + g * 8;
        bf16x8 v = *(const bf16x8*)(qsrc + d0);
        bf16x8 o;
#pragma unroll
        for (int p = 0; p < 4; ++p) {
          float x0 = (float)v[2 * p], x1 = (float)v[2 * p + 1];
          float2 cs = tb[(d0 >> 1) + p];
          o[2 * p]     = (bf16)(x0 * cs.x - x1 * cs.y);
          o[2 * p + 1] = (bf16)(x0 * cs.y + x1 * cs.x);
        }
        aq[ks] = o;
      }
    }

    f32x4 acco[8];
#pragma unroll
    for (int n = 0; n < 8; ++n) acco[n] = (f32x4){0.f, 0.f, 0.f, 0.f};
    float l_r[4] = {0.f, 0.f, 0.f, 0.f};   // per-lane partial denominators

    const int nk = 2 * qt + 2;
    stage(0, 0);
    asm volatile("s_waitcnt vmcnt(0)");
    __builtin_amdgcn_sched_barrier(0);
    __builtin_amdgcn_s_barrier();

    for (int kt = 0; kt < nk; ++kt) {
      int kv0 = kt * 64;
      int cur = kt & 1;
      if (kt + 1 < nk) stage(kv0 + 64, cur ^ 1);   // issue early, lands under compute

      if (kv0 <= qrow0 + 15) {
        f32x4 s[4];
#pragma unroll
        for (int n = 0; n < 4; ++n) s[n] = (f32x4){0.f, 0.f, 0.f, 0.f};
#pragma unroll
        for (int ks = 0; ks < 4; ++ks) {
          int off = ((ks * 64 + g * 16) ^ kxor) >> 1;
#pragma unroll
          for (int n = 0; n < 4; ++n) {
            bf16x8 kb = *(const bf16x8*)&Ks[cur][(n * 16 + l15) * 128 + off];
            s[n] = __builtin_amdgcn_mfma_f32_16x16x32_bf16(aq[ks], kb, s[n], 0, 0, 0);
          }
        }
        if (kv0 + 63 > qrow0) {  // diagonal tile: causal mask
#pragma unroll
          for (int n = 0; n < 4; ++n)
#pragma unroll
            for (int r = 0; r < 4; ++r) {
              int qg = qrow0 + g * 4 + r;
              int kg = kv0 + n * 16 + l15;
              if (kg > qg) s[n][r] = NEG;
            }
        }
        // static-max softmax: P = exp2(s*C2); masked -> exactly 0
#pragma unroll
        for (int n = 0; n < 4; ++n)
#pragma unroll
          for (int r = 0; r < 4; ++r) {
            float p = exp2f(s[n][r] * C2);
            l_r[r] += p;
            int row = g * 4 + r;
            Pw[row * 64 + ((n * 16 + l15) ^ ((row & 7) << 3))] = (bf16)p;
          }
        // P writes -> P reads (wave-local): fence both sides, clobber-free
        __builtin_amdgcn_sched_barrier(0);
        asm volatile("s_waitcnt lgkmcnt(0)");
        __builtin_amdgcn_sched_barrier(0);
#pragma unroll
        for (int ks = 0; ks < 2; ++ks) {
          bf16x8 pa = *(const bf16x8*)&Pw[l15 * 64 + (((ks * 64 + g * 16) ^ kxor) >> 1)];
          int off = ((ks * 64 + g * 16) ^ kxor) >> 1;
#pragma unroll
          for (int n = 0; n < 8; ++n) {
            bf16x8 vb = *(const bf16x8*)&Vs[cur][(n * 16 + l15) * 64 + off];
            acco[n] = __builtin_amdgcn_mfma_f32_16x16x32_bf16(pa, vb, acco[n], 0, 0, 0);
          }
        }
      }

      if (kt + 1 < nk) { asm volatile("s_waitcnt vmcnt(0)"); }
      __builtin_amdgcn_sched_barrier(0);
      __builtin_amdgcn_s_barrier();
    }

    // epilogue: ONE denominator reduce per pass, then normalize and store
#pragma unroll
    for (int r = 0; r < 4; ++r) {
      float ps = l_r[r];
#pragma unroll
      for (int off = 1; off < 16; off <<= 1) ps += __shfl_xor(ps, off);
      float inv = 1.0f / ps;
      int qg = qrow0 + g * 4 + r;
#pragma unroll
      for (int n = 0; n < 8; ++n)
        ctx[(((size_t)b * 2048 + qg) * 32 + h) * 128 + n * 16 + l15] = (bf16)(acco[n][r] * inv);
    }
    __builtin_amdgcn_s_barrier();   // pass boundary before re-staging buf 0
  }
}

// ---------- launcher ----------
extern "C" void kernel_launch(void* const* d_in, const int* in_sizes, int n_in,
                              void* d_out, int out_size, void* d_ws, size_t ws_size,
                              hipStream_t stream) {
  const float* x = (const float*)d_in[0];
  const float* wqkv = (const float*)d_in[1];
  const float* wo = (const float*)d_in[2];
  float* out = (float*)d_out;
  char* ws = (char*)d_ws;

  // workspace layout (bytes); total = 185,597,952
  bf16* xbf    = (bf16*)(ws + 0);            // 33,554,432  (reused as ctx later)
  bf16* wqkvbf = (bf16*)(ws + 33554432);     // 50,331,648
  bf16* qkvbf  = (bf16*)(ws + 83886080);     // 50,331,648  (LIVE until attn done)
  bf16* wobf   = (bf16*)(ws + 134217728);    // 33,554,432  (old qbuf region)
  bf16* kbuf   = (bf16*)(ws + 167772160);    // 8,388,608
  bf16* vtbuf  = (bf16*)(ws + 176160768);    // 8,388,608
  float2* tab  = (float2*)(ws + 184549376);  // 1,048,576

  // 1. merged converts + rope table (one launch)
  init_k<<<20992, 256, 0, stream>>>(x, xbf, wqkv, wqkvbf, tab);

  // 2. QKV projection: 256x192 tiles (32x32 MFMA) -> 512 blocks = 2 exact rounds
  gemm192<bf16><<<dim3(M_ / 256, F_ / 192), 512, 0, stream>>>(xbf, wqkvbf, qkvbf, M_, F_, E_);

  // 3. K-RoPE + V-transpose (Q-RoPE is fused into attn)
  rope_k_k<<<2048, 256, 0, stream>>>(qkvbf, tab, kbuf);
  vtrans_k<<<2048, 256, 0, stream>>>(qkvbf, vtbuf);

  // 4. convert wo into its own region (qkv stays live for attn's Q reads)
  f2bf_k<<<8192, 256, 0, stream>>>(wo, wobf, E_ * E_ / 8);

  // 5. attention (Q from qkv + fused RoPE) -> ctx (xbf region, dead after GEMM1)
  bf16* ctx = xbf;
  attn_k<<<512, 512, 0, stream>>>(qkvbf, kbuf, vtbuf, tab, ctx);

  // 6. output projection: 256x256 tiles -> 16x16 = 256 blocks = 1 exact round
  gemm256<float><<<dim3(M_ / 256, E_ / 256), 512, 0, stream>>>(ctx, wobf, out, M_, E_, E_);
}

// Round 16
// 488.289 us; speedup vs baseline: 1.0454x; 1.0454x over previous
//
#include <hip/hip_runtime.h>
#include <cstdint>

// ---------- types ----------
typedef __bf16 bf16;
typedef __bf16 bf16x8 __attribute__((ext_vector_type(8)));
typedef float  f32x4  __attribute__((ext_vector_type(4)));

#define AS1(p) ((__attribute__((address_space(1))) void*)(p))
#define AS3(p) ((__attribute__((address_space(3))) void*)(p))

__device__ __forceinline__ void gload16(const void* g, void* l) {
  __builtin_amdgcn_global_load_lds(AS1(g), AS3(l), 16, 0, 0);
}

// ---------- problem constants ----------
constexpr int B_ = 2, S_ = 2048, E_ = 4096, H_ = 32, KVH_ = 8, D_ = 128;
constexpr int QPK_ = H_ / KVH_;            // 4
constexpr int F_ = E_ + 2 * KVH_ * D_;     // 6144
constexpr int M_ = B_ * S_;                // 4096 rows of x

// ---------- merged init: x->bf16, wqkv->bf16, rope table (one launch) ----------
__device__ __forceinline__ void conv8(const float* in, bf16* out, int i) {
  const float4* p = (const float4*)(in + (size_t)i * 8);
  float4 a = p[0], b = p[1];
  bf16x8 o;
  o[0] = (bf16)a.x; o[1] = (bf16)a.y; o[2] = (bf16)a.z; o[3] = (bf16)a.w;
  o[4] = (bf16)b.x; o[5] = (bf16)b.y; o[6] = (bf16)b.z; o[7] = (bf16)b.w;
  *(bf16x8*)(out + (size_t)i * 8) = o;
}

__global__ void init_k(const float* __restrict__ x, bf16* __restrict__ xbf,
                       const float* __restrict__ wqkv, bf16* __restrict__ wqkvbf,
                       float2* __restrict__ tab) {
  int i = blockIdx.x * 256 + threadIdx.x;
  if (i < 2097152) {                       // x: 16M elems
    conv8(x, xbf, i);
  } else if (i < 2097152 + 3145728) {      // wqkv: 25.2M elems
    conv8(wqkv, wqkvbf, i - 2097152);
  } else {                                 // rope table: S*64
    int j = i - 5242880;
    if (j < 131072) {
      int s = j >> 6, f = j & 63;
      float inv = powf(10000.0f, -2.0f * (float)f / 128.0f);
      float ang = (float)s * inv;
      tab[j] = make_float2(cosf(ang), sinf(ang));
    }
  }
}

// ---------- fp32 -> bf16 convert (wo only) ----------
__global__ void f2bf_k(const float* __restrict__ in, bf16* __restrict__ out, int n8) {
  int i = blockIdx.x * 256 + threadIdx.x;
  if (i >= n8) return;
  conv8(in, out, i);
}

// ============ 256x192 2-phase bf16 GEMM, 16x16x32 MFMA (GEMM1) ============
// REVERTED to r13/r14 form (210us, conflicts 0). r15's 32x32 variant hit the
// 4-way bank-conflict floor: 128B rows give only 8 16B slots, and its read
// pattern has 32 lanes on 32 distinct rows at one column -> (row&7) swizzle
// can spread at most 8 ways -> 4 lanes/bank-group (1.58x LDS tax, m136),
// conflicts 0 -> 2.1e7, dur +29us. 16x16 reads 16 rows x 4 g-offsets = 2-way
// (free). 512 blocks = 2 exact rounds; B tri-buf; counted vmcnt(3).
template <typename OutT>
__global__ __launch_bounds__(512, 2)
void gemm192(const bf16* __restrict__ A, const bf16* __restrict__ B,
             OutT* __restrict__ C, int M, int N, int K) {
  __shared__ bf16 As[2][256 * 64];   // 32KB each
  __shared__ bf16 Bs[3][192 * 64];   // 24KB each
  const int tid = threadIdx.x;
  const int wid = tid >> 6, lane = tid & 63;
  const int l15 = lane & 15, g = lane >> 4;
  const int wr = wid >> 2, wc = wid & 3;
  const int bm = blockIdx.x, bn = blockIdx.y;
  const bf16* Ab = A + (size_t)bm * 256 * K;
  const bf16* Bb = B + (size_t)bn * 192 * K;
  const int nT = K >> 6;
  const int swzr = (l15 & 7) << 4;   // read-side byte swizzle for row = *+l15

  f32x4 acc[8][3];
#pragma unroll
  for (int m = 0; m < 8; ++m)
#pragma unroll
    for (int n = 0; n < 3; ++n) acc[m][n] = (f32x4){0.f, 0.f, 0.f, 0.f};

  auto stgA = [&](int t) {   // 256x64 tile, 32KB, 4 loads/thread
    bf16* dst = &As[t & 1][0];
#pragma unroll
    for (int i = 0; i < 4; ++i) {
      int lb = i * 8192 + wid * 1024 + lane * 16;
      int row = lb >> 7;
      int colb = (lb & 127) ^ ((row & 7) << 4);
      gload16(Ab + (size_t)row * K + t * 64 + (colb >> 1),
              dst + ((i * 8192 + wid * 1024) >> 1));
    }
  };
  auto stgB = [&](int t) {   // 192x64 tile, 24KB, 3 loads/thread
    bf16* dst = &Bs[t % 3][0];
#pragma unroll
    for (int i = 0; i < 3; ++i) {
      int lb = i * 8192 + wid * 1024 + lane * 16;
      int row = lb >> 7;
      int colb = (lb & 127) ^ ((row & 7) << 4);
      gload16(Bb + (size_t)row * K + t * 64 + (colb >> 1),
              dst + ((i * 8192 + wid * 1024) >> 1));
    }
  };

  // ---- prologue: A0+B0 staged, B1 issued; vmcnt(3) keeps B1 in flight ----
  stgA(0); stgB(0);
  if (nT > 1) { stgB(1); asm volatile("s_waitcnt vmcnt(3)"); }
  else        { asm volatile("s_waitcnt vmcnt(0)"); }
  __builtin_amdgcn_sched_barrier(0);
  __builtin_amdgcn_s_barrier();

  bf16x8 af[4][2], bfr[3][2];
  for (int t = 0; t < nT; ++t) {
    const bf16* Asc = &As[t & 1][0];
    const bf16* Bsc = &Bs[t % 3][0];
    // -------- P1: A-lo (8 reads) + ALL B (6 reads); stage A(t+1) --------
#pragma unroll
    for (int m = 0; m < 4; ++m) {
      int arow = wr * 128 + m * 16 + l15;
#pragma unroll
      for (int ks = 0; ks < 2; ++ks)
        af[m][ks] = *(const bf16x8*)&Asc[(arow << 6) + (((ks * 64 + g * 16) ^ swzr) >> 1)];
    }
#pragma unroll
    for (int n = 0; n < 3; ++n) {
      int brow = wc * 48 + n * 16 + l15;
#pragma unroll
      for (int ks = 0; ks < 2; ++ks)
        bfr[n][ks] = *(const bf16x8*)&Bsc[(brow << 6) + (((ks * 64 + g * 16) ^ swzr) >> 1)];
    }
    if (t + 1 < nT) stgA(t + 1);
    __builtin_amdgcn_s_barrier();
    asm volatile("s_waitcnt lgkmcnt(0)");
    __builtin_amdgcn_sched_barrier(0);
    __builtin_amdgcn_s_setprio(1);
#pragma unroll
    for (int ks = 0; ks < 2; ++ks)
#pragma unroll
      for (int m = 0; m < 4; ++m)
#pragma unroll
        for (int n = 0; n < 3; ++n)
          acc[m][n] = __builtin_amdgcn_mfma_f32_16x16x32_bf16(af[m][ks], bfr[n][ks], acc[m][n], 0, 0, 0);
    __builtin_amdgcn_s_setprio(0);
    __builtin_amdgcn_s_barrier();
    // -------- P2: A-hi (8 reads); stage B(t+2); counted boundary vmcnt ------
#pragma unroll
    for (int m = 0; m < 4; ++m) {
      int arow = wr * 128 + 64 + m * 16 + l15;
#pragma unroll
      for (int ks = 0; ks < 2; ++ks)
        af[m][ks] = *(const bf16x8*)&Asc[(arow << 6) + (((ks * 64 + g * 16) ^ swzr) >> 1)];
    }
    if (t + 2 < nT) stgB(t + 2);
    __builtin_amdgcn_s_barrier();
    asm volatile("s_waitcnt lgkmcnt(0)");
    __builtin_amdgcn_sched_barrier(0);
    __builtin_amdgcn_s_setprio(1);
#pragma unroll
    for (int ks = 0; ks < 2; ++ks)
#pragma unroll
      for (int m = 0; m < 4; ++m)
#pragma unroll
        for (int n = 0; n < 3; ++n)
          acc[4 + m][n] = __builtin_amdgcn_mfma_f32_16x16x32_bf16(af[m][ks], bfr[n][ks], acc[4 + m][n], 0, 0, 0);
    __builtin_amdgcn_s_setprio(0);
    if (t + 2 < nT)      { asm volatile("s_waitcnt vmcnt(3)"); }
    else if (t + 1 < nT) { asm volatile("s_waitcnt vmcnt(0)"); }
    __builtin_amdgcn_sched_barrier(0);
    __builtin_amdgcn_s_barrier();
  }

  // epilogue: C/D layout col=lane&15, row=(lane>>4)*4+r  [measured m89]
#pragma unroll
  for (int m = 0; m < 8; ++m) {
    int row0 = bm * 256 + wr * 128 + m * 16 + g * 4;
#pragma unroll
    for (int n = 0; n < 3; ++n) {
      int col = bn * 192 + wc * 48 + n * 16 + l15;
      f32x4 v = acc[m][n];
#pragma unroll
      for (int r = 0; r < 4; ++r)
        C[(size_t)(row0 + r) * N + col] = (OutT)v[r];
    }
  }
}

// ============ 256x256 4-phase bf16 GEMM, pair-unrolled (GEMM3, r7 proven) =====
template <typename OutT>
__global__ __launch_bounds__(512, 2)
void gemm256(const bf16* __restrict__ A, const bf16* __restrict__ B,
             OutT* __restrict__ C, int M, int N, int K) {
  __shared__ bf16 As[2][16384];
  __shared__ bf16 Bs[2][16384];
  const int tid = threadIdx.x;
  const int wid = tid >> 6, lane = tid & 63;
  const int l15 = lane & 15, g = lane >> 4;
  const int wr = wid >> 2, wc = wid & 3;
  const int bm = blockIdx.x, bn = blockIdx.y;
  const bf16* Ab = A + (size_t)bm * 256 * K;
  const bf16* Bb = B + (size_t)bn * 256 * K;
  const int nT = K >> 6;
  const int swzr = (l15 & 7) << 4;

  f32x4 acc[8][4];
#pragma unroll
  for (int m = 0; m < 8; ++m)
#pragma unroll
    for (int n = 0; n < 4; ++n) acc[m][n] = (f32x4){0.f, 0.f, 0.f, 0.f};

  auto stg = [&](const bf16* src, bf16* dst, int t, int h) {
#pragma unroll
    for (int i = 0; i < 2; ++i) {
      int lb = h * 16384 + i * 8192 + wid * 1024 + lane * 16;
      int row = lb >> 7;
      int colb = (lb & 127) ^ ((row & 7) << 4);
      gload16(src + (size_t)row * K + t * 64 + (colb >> 1),
              dst + ((h * 16384 + i * 8192 + wid * 1024) >> 1));
    }
  };

  bf16x8 af[4][2];
  bf16x8 bfr[2][2][2];

  stg(Bb, Bs[0], 0, 0); stg(Bb, Bs[0], 0, 1);
  stg(Ab, As[0], 0, 0); stg(Ab, As[0], 0, 1);
  if (nT > 1) {
    stg(Bb, Bs[1], 1, 0); stg(Bb, Bs[1], 1, 1);
    asm volatile("s_waitcnt vmcnt(4)");
  } else {
    asm volatile("s_waitcnt vmcnt(0)");
  }
  __builtin_amdgcn_sched_barrier(0);
  __builtin_amdgcn_s_barrier();

  auto tileK = [&](int t, const int cur) {
    // P1
#pragma unroll
    for (int m = 0; m < 4; ++m) {
      int arow = wr * 128 + m * 16 + l15;
#pragma unroll
      for (int ks = 0; ks < 2; ++ks)
        af[m][ks] = *(const bf16x8*)&As[cur][(arow << 6) + (((ks * 64 + g * 16) ^ swzr) >> 1)];
    }
#pragma unroll
    for (int n = 0; n < 2; ++n) {
      int brow = wc * 64 + n * 16 + l15;
#pragma unroll
      for (int ks = 0; ks < 2; ++ks)
        bfr[0][n][ks] = *(const bf16x8*)&Bs[cur][(brow << 6) + (((ks * 64 + g * 16) ^ swzr) >> 1)];
    }
    if (t + 1 < nT) stg(Ab, As[cur ^ 1], t + 1, 0);
    __builtin_amdgcn_s_barrier();
    asm volatile("s_waitcnt lgkmcnt(0)");
    __builtin_amdgcn_s_setprio(1);
#pragma unroll
    for (int ks = 0; ks < 2; ++ks)
#pragma unroll
      for (int m = 0; m < 4; ++m)
#pragma unroll
        for (int n = 0; n < 2; ++n)
          acc[m][n] = __builtin_amdgcn_mfma_f32_16x16x32_bf16(af[m][ks], bfr[0][n][ks], acc[m][n], 0, 0, 0);
    __builtin_amdgcn_s_setprio(0);
    __builtin_amdgcn_s_barrier();
    // P2
#pragma unroll
    for (int n = 0; n < 2; ++n) {
      int brow = wc * 64 + 32 + n * 16 + l15;
#pragma unroll
      for (int ks = 0; ks < 2; ++ks)
        bfr[1][n][ks] = *(const bf16x8*)&Bs[cur][(brow << 6) + (((ks * 64 + g * 16) ^ swzr) >> 1)];
    }
    if (t + 1 < nT) stg(Ab, As[cur ^ 1], t + 1, 1);
    __builtin_amdgcn_s_barrier();
    asm volatile("s_waitcnt lgkmcnt(0)");
    __builtin_amdgcn_s_setprio(1);
#pragma unroll
    for (int ks = 0; ks < 2; ++ks)
#pragma unroll
      for (int m = 0; m < 4; ++m)
#pragma unroll
        for (int n = 0; n < 2; ++n)
          acc[m][2 + n] = __builtin_amdgcn_mfma_f32_16x16x32_bf16(af[m][ks], bfr[1][n][ks], acc[m][2 + n], 0, 0, 0);
    __builtin_amdgcn_s_setprio(0);
    __builtin_amdgcn_s_barrier();
    // P3
#pragma unroll
    for (int m = 0; m < 4; ++m) {
      int arow = wr * 128 + 64 + m * 16 + l15;
#pragma unroll
      for (int ks = 0; ks < 2; ++ks)
        af[m][ks] = *(const bf16x8*)&As[cur][(arow << 6) + (((ks * 64 + g * 16) ^ swzr) >> 1)];
    }
    if (t + 2 < nT) stg(Bb, Bs[cur], t + 2, 0);
    __builtin_amdgcn_s_barrier();
    asm volatile("s_waitcnt lgkmcnt(0)");
    __builtin_amdgcn_s_setprio(1);
#pragma unroll
    for (int ks = 0; ks < 2; ++ks)
#pragma unroll
      for (int m = 0; m < 4; ++m)
#pragma unroll
        for (int n = 0; n < 2; ++n)
          acc[4 + m][n] = __builtin_amdgcn_mfma_f32_16x16x32_bf16(af[m][ks], bfr[0][n][ks], acc[4 + m][n], 0, 0, 0);
    __builtin_amdgcn_s_setprio(0);
    __builtin_amdgcn_s_barrier();
    // P4
    if (t + 2 < nT) stg(Bb, Bs[cur], t + 2, 1);
    __builtin_amdgcn_s_setprio(1);
#pragma unroll
    for (int ks = 0; ks < 2; ++ks)
#pragma unroll
      for (int m = 0; m < 4; ++m)
#pragma unroll
        for (int n = 0; n < 2; ++n)
          acc[4 + m][2 + n] = __builtin_amdgcn_mfma_f32_16x16x32_bf16(af[m][ks], bfr[1][n][ks], acc[4 + m][2 + n], 0, 0, 0);
    __builtin_amdgcn_s_setprio(0);
    if (t + 2 < nT)      { asm volatile("s_waitcnt vmcnt(4)"); }
    else if (t + 1 < nT) { asm volatile("s_waitcnt vmcnt(0)"); }
    __builtin_amdgcn_sched_barrier(0);
    __builtin_amdgcn_s_barrier();
  };

  for (int tt = 0; tt < nT; tt += 2) {
    tileK(tt, 0);
    tileK(tt + 1, 1);
  }

#pragma unroll
  for (int mh = 0; mh < 2; ++mh)
#pragma unroll
    for (int m = 0; m < 4; ++m) {
      int row0 = bm * 256 + wr * 128 + mh * 64 + m * 16 + g * 4;
#pragma unroll
      for (int nh = 0; nh < 2; ++nh)
#pragma unroll
        for (int n = 0; n < 2; ++n) {
          int col = bn * 256 + wc * 64 + nh * 32 + n * 16 + l15;
          f32x4 v = acc[mh * 4 + m][nh * 2 + n];
#pragma unroll
          for (int r = 0; r < 4; ++r)
            C[(size_t)(row0 + r) * N + col] = (OutT)v[r];
        }
    }
}

// ---------- RoPE on K: qkv -> k[B][KVH][S][D] ----------
__global__ void rope_k_k(const bf16* __restrict__ qkv, const float2* __restrict__ tab,
                         bf16* __restrict__ kout) {
  int idx = blockIdx.x * 256 + threadIdx.x;  // B*S*KVH*16 = 524288
  int c = idx & 15;
  int kvh = (idx >> 4) & 7;
  int s = (idx >> 7) & 2047;
  int b = idx >> 18;
  int d0 = c * 8;
  const bf16* src = qkv + (size_t)(b * 2048 + s) * F_ + kvh * (QPK_ + 2) * D_ + QPK_ * D_ + d0;
  bf16x8 v = *(const bf16x8*)src;
  const float2* tb = tab + s * 64 + (d0 >> 1);
  bf16x8 o;
#pragma unroll
  for (int p = 0; p < 4; ++p) {
    float x0 = (float)v[2 * p], x1 = (float)v[2 * p + 1];
    float2 cs = tb[p];
    o[2 * p]     = (bf16)(x0 * cs.x - x1 * cs.y);
    o[2 * p + 1] = (bf16)(x0 * cs.y + x1 * cs.x);
  }
  *(bf16x8*)(kout + ((size_t)(b * 8 + kvh) * 2048 + s) * 128 + d0) = o;
}

// ---------- V transpose: qkv -> vt[B][KVH][D][S] (LDS tiled 64s x 32d) ----------
__global__ void vtrans_k(const bf16* __restrict__ qkv, bf16* __restrict__ vt) {
  int bidx = blockIdx.x;  // B*KVH*4*32 = 2048
  int st = bidx & 31;
  int dt = (bidx >> 5) & 3;
  int kvh = (bidx >> 7) & 7;
  int b = bidx >> 10;
  __shared__ bf16 tile[64][40];
  int t = threadIdx.x;
  {
    int sl = t >> 2, d0 = (t & 3) * 8;
    bf16x8 v = *(const bf16x8*)(qkv + (size_t)(b * 2048 + st * 64 + sl) * F_ +
                                kvh * (QPK_ + 2) * D_ + (QPK_ + 1) * D_ + dt * 32 + d0);
#pragma unroll
    for (int i = 0; i < 8; ++i) tile[sl][d0 + i] = v[i];
  }
  __syncthreads();
  {
    int dl = t >> 3, s0 = (t & 7) * 8;
    bf16x8 o;
#pragma unroll
    for (int i = 0; i < 8; ++i) o[i] = tile[s0 + i][dl];
    *(bf16x8*)(vt + ((size_t)(b * 8 + kvh) * 128 + dt * 32 + dl) * 2048 + st * 64 + s0) = o;
  }
}

// ---------- causal GQA flash attention (r14 structure + fused Q-RoPE) ----
__global__ __launch_bounds__(512, 4)
void attn_k(const bf16* __restrict__ qkv, const bf16* __restrict__ k,
            const bf16* __restrict__ vt, const float2* __restrict__ tab,
            bf16* __restrict__ ctx) {
  int bid = blockIdx.x;
  bid = (bid & 7) * 64 + (bid >> 3);   // XCD chunk: each XCD gets 2 (b,kvh) KV sets
  int qp = bid & 7;
  int h = (bid >> 3) & 31;
  int b = bid >> 8;
  int kvh = h >> 2, j = h & 3;
  int tid = threadIdx.x, w = tid >> 6, lane = tid & 63;
  int l15 = lane & 15, g = lane >> 4;

  __shared__ bf16 Ks[2][64 * 128];   // 32KB
  __shared__ bf16 Vs[2][128 * 64];   // 32KB
  __shared__ bf16 Plds[8][16 * 64];  // 16KB, XOR-swizzled rows (128B)

  bf16* Pw = &Plds[w][0];
  const float C2 = 0.08838834764831845f * 1.4426950408889634f;  // scale * log2(e)
  const float NEG = -3.0e38f;

  const bf16* kb_base = k + (size_t)(b * 8 + kvh) * 2048 * 128;
  const bf16* vt_base = vt + (size_t)(b * 8 + kvh) * 128 * 2048;

  auto stage = [&](int kv0, int buf) {
#pragma unroll
    for (int i = 0; i < 2; ++i) {
      int lt = i * 8192 + tid * 16;
      int row = lt >> 8;
      int ch = (lt >> 4) & 15;
      int srcel = (ch ^ (row & 7)) << 3;
      gload16(kb_base + (size_t)(kv0 + row) * 128 + srcel,
              &Ks[buf][(i * 8192 + w * 1024) >> 1]);
    }
#pragma unroll
    for (int i = 0; i < 2; ++i) {
      int lt = i * 8192 + tid * 16;
      int row = lt >> 7;
      int ch = (lt >> 4) & 7;
      int srcel = (ch ^ (row & 7)) << 3;
      gload16(vt_base + (size_t)row * 2048 + kv0 + srcel,
              &Vs[buf][(i * 8192 + w * 1024) >> 1]);
    }
  };

  const int kxor = (l15 & 7) << 4;   // read-side byte swizzle (row = *+l15)

  for (int pass = 0; pass < 2; ++pass) {
    int qt = pass ? (15 - qp) : qp;
    int qrow0 = qt * 128 + w * 16;

    // Q fragments: read from qkv + apply RoPE in-register (lane-local pairs)
    bf16x8 aq[4];
    {
      int s = qrow0 + l15;
      const bf16* qsrc = qkv + (size_t)(b * 2048 + s) * F_ + kvh * (QPK_ + 2) * D_ + j * D_;
      const float2* tb = tab + s * 64;
#pragma unroll
      for (int ks = 0; ks < 4; ++ks) {
        int d0 = ks * 32 + g * 8;
        bf16x8 v = *(const bf16x8*)(qsrc + d0);
        bf16x8 o;
#pragma unroll
        for (int p = 0; p < 4; ++p) {
          float x0 = (float)v[2 * p], x1 = (float)v[2 * p + 1];
          float2 cs = tb[(d0 >> 1) + p];
          o[2 * p]     = (bf16)(x0 * cs.x - x1 * cs.y);
          o[2 * p + 1] = (bf16)(x0 * cs.y + x1 * cs.x);
        }
        aq[ks] = o;
      }
    }

    f32x4 acco[8];
#pragma unroll
    for (int n = 0; n < 8; ++n) acco[n] = (f32x4){0.f, 0.f, 0.f, 0.f};
    float l_r[4] = {0.f, 0.f, 0.f, 0.f};   // per-lane partial denominators

    const int nk = 2 * qt + 2;
    stage(0, 0);
    asm volatile("s_waitcnt vmcnt(0)");
    __builtin_amdgcn_sched_barrier(0);
    __builtin_amdgcn_s_barrier();

    for (int kt = 0; kt < nk; ++kt) {
      int kv0 = kt * 64;
      int cur = kt & 1;
      if (kt + 1 < nk) stage(kv0 + 64, cur ^ 1);   // issue early, lands under compute

      if (kv0 <= qrow0 + 15) {
        f32x4 s[4];
#pragma unroll
        for (int n = 0; n < 4; ++n) s[n] = (f32x4){0.f, 0.f, 0.f, 0.f};
#pragma unroll
        for (int ks = 0; ks < 4; ++ks) {
          int off = ((ks * 64 + g * 16) ^ kxor) >> 1;
#pragma unroll
          for (int n = 0; n < 4; ++n) {
            bf16x8 kb = *(const bf16x8*)&Ks[cur][(n * 16 + l15) * 128 + off];
            s[n] = __builtin_amdgcn_mfma_f32_16x16x32_bf16(aq[ks], kb, s[n], 0, 0, 0);
          }
        }
        if (kv0 + 63 > qrow0) {  // diagonal tile: causal mask
#pragma unroll
          for (int n = 0; n < 4; ++n)
#pragma unroll
            for (int r = 0; r < 4; ++r) {
              int qg = qrow0 + g * 4 + r;
              int kg = kv0 + n * 16 + l15;
              if (kg > qg) s[n][r] = NEG;
            }
        }
        // static-max softmax: P = exp2(s*C2); masked -> exactly 0
#pragma unroll
        for (int n = 0; n < 4; ++n)
#pragma unroll
          for (int r = 0; r < 4; ++r) {
            float p = exp2f(s[n][r] * C2);
            l_r[r] += p;
            int row = g * 4 + r;
            Pw[row * 64 + ((n * 16 + l15) ^ ((row & 7) << 3))] = (bf16)p;
          }
        // P writes -> P reads (wave-local): fence both sides, clobber-free
        __builtin_amdgcn_sched_barrier(0);
        asm volatile("s_waitcnt lgkmcnt(0)");
        __builtin_amdgcn_sched_barrier(0);
#pragma unroll
        for (int ks = 0; ks < 2; ++ks) {
          bf16x8 pa = *(const bf16x8*)&Pw[l15 * 64 + (((ks * 64 + g * 16) ^ kxor) >> 1)];
          int off = ((ks * 64 + g * 16) ^ kxor) >> 1;
#pragma unroll
          for (int n = 0; n < 8; ++n) {
            bf16x8 vb = *(const bf16x8*)&Vs[cur][(n * 16 + l15) * 64 + off];
            acco[n] = __builtin_amdgcn_mfma_f32_16x16x32_bf16(pa, vb, acco[n], 0, 0, 0);
          }
        }
      }

      if (kt + 1 < nk) { asm volatile("s_waitcnt vmcnt(0)"); }
      __builtin_amdgcn_sched_barrier(0);
      __builtin_amdgcn_s_barrier();
    }

    // epilogue: ONE denominator reduce per pass, then normalize and store
#pragma unroll
    for (int r = 0; r < 4; ++r) {
      float ps = l_r[r];
#pragma unroll
      for (int off = 1; off < 16; off <<= 1) ps += __shfl_xor(ps, off);
      float inv = 1.0f / ps;
      int qg = qrow0 + g * 4 + r;
#pragma unroll
      for (int n = 0; n < 8; ++n)
        ctx[(((size_t)b * 2048 + qg) * 32 + h) * 128 + n * 16 + l15] = (bf16)(acco[n][r] * inv);
    }
    __builtin_amdgcn_s_barrier();   // pass boundary before re-staging buf 0
  }
}

// ---------- launcher ----------
extern "C" void kernel_launch(void* const* d_in, const int* in_sizes, int n_in,
                              void* d_out, int out_size, void* d_ws, size_t ws_size,
                              hipStream_t stream) {
  const float* x = (const float*)d_in[0];
  const float* wqkv = (const float*)d_in[1];
  const float* wo = (const float*)d_in[2];
  float* out = (float*)d_out;
  char* ws = (char*)d_ws;

  // workspace layout (bytes); total = 185,597,952
  bf16* xbf    = (bf16*)(ws + 0);            // 33,554,432  (reused as ctx later)
  bf16* wqkvbf = (bf16*)(ws + 33554432);     // 50,331,648
  bf16* qkvbf  = (bf16*)(ws + 83886080);     // 50,331,648  (LIVE until attn done)
  bf16* wobf   = (bf16*)(ws + 134217728);    // 33,554,432  (old qbuf region)
  bf16* kbuf   = (bf16*)(ws + 167772160);    // 8,388,608
  bf16* vtbuf  = (bf16*)(ws + 176160768);    // 8,388,608
  float2* tab  = (float2*)(ws + 184549376);  // 1,048,576

  // 1. merged converts + rope table (one launch)
  init_k<<<20992, 256, 0, stream>>>(x, xbf, wqkv, wqkvbf, tab);

  // 2. QKV projection: 256x192 tiles (16x16 MFMA) -> 512 blocks = 2 exact rounds
  gemm192<bf16><<<dim3(M_ / 256, F_ / 192), 512, 0, stream>>>(xbf, wqkvbf, qkvbf, M_, F_, E_);

  // 3. K-RoPE + V-transpose (Q-RoPE is fused into attn)
  rope_k_k<<<2048, 256, 0, stream>>>(qkvbf, tab, kbuf);
  vtrans_k<<<2048, 256, 0, stream>>>(qkvbf, vtbuf);

  // 4. convert wo into its own region (qkv stays live for attn's Q reads)
  f2bf_k<<<8192, 256, 0, stream>>>(wo, wobf, E_ * E_ / 8);

  // 5. attention (Q from qkv + fused RoPE) -> ctx (xbf region, dead after GEMM1)
  bf16* ctx = xbf;
  attn_k<<<512, 512, 0, stream>>>(qkvbf, kbuf, vtbuf, tab, ctx);

  // 6. output projection: 256x256 tiles -> 16x16 = 256 blocks = 1 exact round
  gemm256<float><<<dim3(M_ / 256, E_ / 256), 512, 0, stream>>>(ctx, wobf, out, M_, E_, E_);
}

// Round 17
// 485.244 us; speedup vs baseline: 1.0520x; 1.0063x over previous
//
#include <hip/hip_runtime.h>
#include <cstdint>

// ---------- types ----------
typedef __bf16 bf16;
typedef __bf16 bf16x8 __attribute__((ext_vector_type(8)));
typedef float  f32x4  __attribute__((ext_vector_type(4)));

#define AS1(p) ((__attribute__((address_space(1))) void*)(p))
#define AS3(p) ((__attribute__((address_space(3))) void*)(p))

__device__ __forceinline__ void gload16(const void* g, void* l) {
  __builtin_amdgcn_global_load_lds(AS1(g), AS3(l), 16, 0, 0);
}

// ---------- problem constants ----------
constexpr int B_ = 2, S_ = 2048, E_ = 4096, H_ = 32, KVH_ = 8, D_ = 128;
constexpr int QPK_ = H_ / KVH_;            // 4
constexpr int F_ = E_ + 2 * KVH_ * D_;     // 6144
constexpr int M_ = B_ * S_;                // 4096 rows of x

// ---------- merged init: x->bf16, wqkv->bf16, wo->bf16, rope table ----------
__device__ __forceinline__ void conv8(const float* in, bf16* out, int i) {
  const float4* p = (const float4*)(in + (size_t)i * 8);
  float4 a = p[0], b = p[1];
  bf16x8 o;
  o[0] = (bf16)a.x; o[1] = (bf16)a.y; o[2] = (bf16)a.z; o[3] = (bf16)a.w;
  o[4] = (bf16)b.x; o[5] = (bf16)b.y; o[6] = (bf16)b.z; o[7] = (bf16)b.w;
  *(bf16x8*)(out + (size_t)i * 8) = o;
}

// grid: 29184 blocks x 256 = 7,471,104 threads
// [0, 2097152)                      : x      (16.8M elems / 8)
// [2097152, 5242880)                : wqkv   (25.2M / 8)
// [5242880, 7340032)                : wo     (16.8M / 8)
// [7340032, 7471104)                : rope table (131072 entries)
__global__ void init_k(const float* __restrict__ x, bf16* __restrict__ xbf,
                       const float* __restrict__ wqkv, bf16* __restrict__ wqkvbf,
                       const float* __restrict__ wo, bf16* __restrict__ wobf,
                       float2* __restrict__ tab) {
  int i = blockIdx.x * 256 + threadIdx.x;
  if (i < 2097152) {
    conv8(x, xbf, i);
  } else if (i < 5242880) {
    conv8(wqkv, wqkvbf, i - 2097152);
  } else if (i < 7340032) {
    conv8(wo, wobf, i - 5242880);
  } else {
    int j = i - 7340032;
    if (j < 131072) {
      int s = j >> 6, f = j & 63;
      float inv = powf(10000.0f, -2.0f * (float)f / 128.0f);
      float ang = (float)s * inv;
      tab[j] = make_float2(cosf(ang), sinf(ang));
    }
  }
}

// ============ 256x192 2-phase bf16 GEMM, 16x16x32 MFMA (GEMM1) ============
// r16-proven: 210us, MfmaUtil 44%, conflicts 0. 512 blocks = 2 exact rounds;
// B tri-buf; counted vmcnt(3); raw barriers + clobber-free waits; setprio.
template <typename OutT>
__global__ __launch_bounds__(512, 2)
void gemm192(const bf16* __restrict__ A, const bf16* __restrict__ B,
             OutT* __restrict__ C, int M, int N, int K) {
  __shared__ bf16 As[2][256 * 64];   // 32KB each
  __shared__ bf16 Bs[3][192 * 64];   // 24KB each
  const int tid = threadIdx.x;
  const int wid = tid >> 6, lane = tid & 63;
  const int l15 = lane & 15, g = lane >> 4;
  const int wr = wid >> 2, wc = wid & 3;
  const int bm = blockIdx.x, bn = blockIdx.y;
  const bf16* Ab = A + (size_t)bm * 256 * K;
  const bf16* Bb = B + (size_t)bn * 192 * K;
  const int nT = K >> 6;
  const int swzr = (l15 & 7) << 4;   // read-side byte swizzle for row = *+l15

  f32x4 acc[8][3];
#pragma unroll
  for (int m = 0; m < 8; ++m)
#pragma unroll
    for (int n = 0; n < 3; ++n) acc[m][n] = (f32x4){0.f, 0.f, 0.f, 0.f};

  auto stgA = [&](int t) {   // 256x64 tile, 32KB, 4 loads/thread
    bf16* dst = &As[t & 1][0];
#pragma unroll
    for (int i = 0; i < 4; ++i) {
      int lb = i * 8192 + wid * 1024 + lane * 16;
      int row = lb >> 7;
      int colb = (lb & 127) ^ ((row & 7) << 4);
      gload16(Ab + (size_t)row * K + t * 64 + (colb >> 1),
              dst + ((i * 8192 + wid * 1024) >> 1));
    }
  };
  auto stgB = [&](int t) {   // 192x64 tile, 24KB, 3 loads/thread
    bf16* dst = &Bs[t % 3][0];
#pragma unroll
    for (int i = 0; i < 3; ++i) {
      int lb = i * 8192 + wid * 1024 + lane * 16;
      int row = lb >> 7;
      int colb = (lb & 127) ^ ((row & 7) << 4);
      gload16(Bb + (size_t)row * K + t * 64 + (colb >> 1),
              dst + ((i * 8192 + wid * 1024) >> 1));
    }
  };

  // ---- prologue: A0+B0 staged, B1 issued; vmcnt(3) keeps B1 in flight ----
  stgA(0); stgB(0);
  if (nT > 1) { stgB(1); asm volatile("s_waitcnt vmcnt(3)"); }
  else        { asm volatile("s_waitcnt vmcnt(0)"); }
  __builtin_amdgcn_sched_barrier(0);
  __builtin_amdgcn_s_barrier();

  bf16x8 af[4][2], bfr[3][2];
  for (int t = 0; t < nT; ++t) {
    const bf16* Asc = &As[t & 1][0];
    const bf16* Bsc = &Bs[t % 3][0];
    // -------- P1: A-lo (8 reads) + ALL B (6 reads); stage A(t+1) --------
#pragma unroll
    for (int m = 0; m < 4; ++m) {
      int arow = wr * 128 + m * 16 + l15;
#pragma unroll
      for (int ks = 0; ks < 2; ++ks)
        af[m][ks] = *(const bf16x8*)&Asc[(arow << 6) + (((ks * 64 + g * 16) ^ swzr) >> 1)];
    }
#pragma unroll
    for (int n = 0; n < 3; ++n) {
      int brow = wc * 48 + n * 16 + l15;
#pragma unroll
      for (int ks = 0; ks < 2; ++ks)
        bfr[n][ks] = *(const bf16x8*)&Bsc[(brow << 6) + (((ks * 64 + g * 16) ^ swzr) >> 1)];
    }
    if (t + 1 < nT) stgA(t + 1);
    __builtin_amdgcn_s_barrier();
    asm volatile("s_waitcnt lgkmcnt(0)");
    __builtin_amdgcn_sched_barrier(0);
    __builtin_amdgcn_s_setprio(1);
#pragma unroll
    for (int ks = 0; ks < 2; ++ks)
#pragma unroll
      for (int m = 0; m < 4; ++m)
#pragma unroll
        for (int n = 0; n < 3; ++n)
          acc[m][n] = __builtin_amdgcn_mfma_f32_16x16x32_bf16(af[m][ks], bfr[n][ks], acc[m][n], 0, 0, 0);
    __builtin_amdgcn_s_setprio(0);
    __builtin_amdgcn_s_barrier();
    // -------- P2: A-hi (8 reads); stage B(t+2); counted boundary vmcnt ------
#pragma unroll
    for (int m = 0; m < 4; ++m) {
      int arow = wr * 128 + 64 + m * 16 + l15;
#pragma unroll
      for (int ks = 0; ks < 2; ++ks)
        af[m][ks] = *(const bf16x8*)&Asc[(arow << 6) + (((ks * 64 + g * 16) ^ swzr) >> 1)];
    }
    if (t + 2 < nT) stgB(t + 2);
    __builtin_amdgcn_s_barrier();
    asm volatile("s_waitcnt lgkmcnt(0)");
    __builtin_amdgcn_sched_barrier(0);
    __builtin_amdgcn_s_setprio(1);
#pragma unroll
    for (int ks = 0; ks < 2; ++ks)
#pragma unroll
      for (int m = 0; m < 4; ++m)
#pragma unroll
        for (int n = 0; n < 3; ++n)
          acc[4 + m][n] = __builtin_amdgcn_mfma_f32_16x16x32_bf16(af[m][ks], bfr[n][ks], acc[4 + m][n], 0, 0, 0);
    __builtin_amdgcn_s_setprio(0);
    if (t + 2 < nT)      { asm volatile("s_waitcnt vmcnt(3)"); }
    else if (t + 1 < nT) { asm volatile("s_waitcnt vmcnt(0)"); }
    __builtin_amdgcn_sched_barrier(0);
    __builtin_amdgcn_s_barrier();
  }

  // epilogue: C/D layout col=lane&15, row=(lane>>4)*4+r  [measured m89]
#pragma unroll
  for (int m = 0; m < 8; ++m) {
    int row0 = bm * 256 + wr * 128 + m * 16 + g * 4;
#pragma unroll
    for (int n = 0; n < 3; ++n) {
      int col = bn * 192 + wc * 48 + n * 16 + l15;
      f32x4 v = acc[m][n];
#pragma unroll
      for (int r = 0; r < 4; ++r)
        C[(size_t)(row0 + r) * N + col] = (OutT)v[r];
    }
  }
}

// ============ 256x256 4-phase bf16 GEMM, pair-unrolled (GEMM3, r7 proven) =====
template <typename OutT>
__global__ __launch_bounds__(512, 2)
void gemm256(const bf16* __restrict__ A, const bf16* __restrict__ B,
             OutT* __restrict__ C, int M, int N, int K) {
  __shared__ bf16 As[2][16384];
  __shared__ bf16 Bs[2][16384];
  const int tid = threadIdx.x;
  const int wid = tid >> 6, lane = tid & 63;
  const int l15 = lane & 15, g = lane >> 4;
  const int wr = wid >> 2, wc = wid & 3;
  const int bm = blockIdx.x, bn = blockIdx.y;
  const bf16* Ab = A + (size_t)bm * 256 * K;
  const bf16* Bb = B + (size_t)bn * 256 * K;
  const int nT = K >> 6;
  const int swzr = (l15 & 7) << 4;

  f32x4 acc[8][4];
#pragma unroll
  for (int m = 0; m < 8; ++m)
#pragma unroll
    for (int n = 0; n < 4; ++n) acc[m][n] = (f32x4){0.f, 0.f, 0.f, 0.f};

  auto stg = [&](const bf16* src, bf16* dst, int t, int h) {
#pragma unroll
    for (int i = 0; i < 2; ++i) {
      int lb = h * 16384 + i * 8192 + wid * 1024 + lane * 16;
      int row = lb >> 7;
      int colb = (lb & 127) ^ ((row & 7) << 4);
      gload16(src + (size_t)row * K + t * 64 + (colb >> 1),
              dst + ((h * 16384 + i * 8192 + wid * 1024) >> 1));
    }
  };

  bf16x8 af[4][2];
  bf16x8 bfr[2][2][2];

  stg(Bb, Bs[0], 0, 0); stg(Bb, Bs[0], 0, 1);
  stg(Ab, As[0], 0, 0); stg(Ab, As[0], 0, 1);
  if (nT > 1) {
    stg(Bb, Bs[1], 1, 0); stg(Bb, Bs[1], 1, 1);
    asm volatile("s_waitcnt vmcnt(4)");
  } else {
    asm volatile("s_waitcnt vmcnt(0)");
  }
  __builtin_amdgcn_sched_barrier(0);
  __builtin_amdgcn_s_barrier();

  auto tileK = [&](int t, const int cur) {
    // P1
#pragma unroll
    for (int m = 0; m < 4; ++m) {
      int arow = wr * 128 + m * 16 + l15;
#pragma unroll
      for (int ks = 0; ks < 2; ++ks)
        af[m][ks] = *(const bf16x8*)&As[cur][(arow << 6) + (((ks * 64 + g * 16) ^ swzr) >> 1)];
    }
#pragma unroll
    for (int n = 0; n < 2; ++n) {
      int brow = wc * 64 + n * 16 + l15;
#pragma unroll
      for (int ks = 0; ks < 2; ++ks)
        bfr[0][n][ks] = *(const bf16x8*)&Bs[cur][(brow << 6) + (((ks * 64 + g * 16) ^ swzr) >> 1)];
    }
    if (t + 1 < nT) stg(Ab, As[cur ^ 1], t + 1, 0);
    __builtin_amdgcn_s_barrier();
    asm volatile("s_waitcnt lgkmcnt(0)");
    __builtin_amdgcn_s_setprio(1);
#pragma unroll
    for (int ks = 0; ks < 2; ++ks)
#pragma unroll
      for (int m = 0; m < 4; ++m)
#pragma unroll
        for (int n = 0; n < 2; ++n)
          acc[m][n] = __builtin_amdgcn_mfma_f32_16x16x32_bf16(af[m][ks], bfr[0][n][ks], acc[m][n], 0, 0, 0);
    __builtin_amdgcn_s_setprio(0);
    __builtin_amdgcn_s_barrier();
    // P2
#pragma unroll
    for (int n = 0; n < 2; ++n) {
      int brow = wc * 64 + 32 + n * 16 + l15;
#pragma unroll
      for (int ks = 0; ks < 2; ++ks)
        bfr[1][n][ks] = *(const bf16x8*)&Bs[cur][(brow << 6) + (((ks * 64 + g * 16) ^ swzr) >> 1)];
    }
    if (t + 1 < nT) stg(Ab, As[cur ^ 1], t + 1, 1);
    __builtin_amdgcn_s_barrier();
    asm volatile("s_waitcnt lgkmcnt(0)");
    __builtin_amdgcn_s_setprio(1);
#pragma unroll
    for (int ks = 0; ks < 2; ++ks)
#pragma unroll
      for (int m = 0; m < 4; ++m)
#pragma unroll
        for (int n = 0; n < 2; ++n)
          acc[m][2 + n] = __builtin_amdgcn_mfma_f32_16x16x32_bf16(af[m][ks], bfr[1][n][ks], acc[m][2 + n], 0, 0, 0);
    __builtin_amdgcn_s_setprio(0);
    __builtin_amdgcn_s_barrier();
    // P3
#pragma unroll
    for (int m = 0; m < 4; ++m) {
      int arow = wr * 128 + 64 + m * 16 + l15;
#pragma unroll
      for (int ks = 0; ks < 2; ++ks)
        af[m][ks] = *(const bf16x8*)&As[cur][(arow << 6) + (((ks * 64 + g * 16) ^ swzr) >> 1)];
    }
    if (t + 2 < nT) stg(Bb, Bs[cur], t + 2, 0);
    __builtin_amdgcn_s_barrier();
    asm volatile("s_waitcnt lgkmcnt(0)");
    __builtin_amdgcn_s_setprio(1);
#pragma unroll
    for (int ks = 0; ks < 2; ++ks)
#pragma unroll
      for (int m = 0; m < 4; ++m)
#pragma unroll
        for (int n = 0; n < 2; ++n)
          acc[4 + m][n] = __builtin_amdgcn_mfma_f32_16x16x32_bf16(af[m][ks], bfr[0][n][ks], acc[4 + m][n], 0, 0, 0);
    __builtin_amdgcn_s_setprio(0);
    __builtin_amdgcn_s_barrier();
    // P4
    if (t + 2 < nT) stg(Bb, Bs[cur], t + 2, 1);
    __builtin_amdgcn_s_setprio(1);
#pragma unroll
    for (int ks = 0; ks < 2; ++ks)
#pragma unroll
      for (int m = 0; m < 4; ++m)
#pragma unroll
        for (int n = 0; n < 2; ++n)
          acc[4 + m][2 + n] = __builtin_amdgcn_mfma_f32_16x16x32_bf16(af[m][ks], bfr[1][n][ks], acc[4 + m][2 + n], 0, 0, 0);
    __builtin_amdgcn_s_setprio(0);
    if (t + 2 < nT)      { asm volatile("s_waitcnt vmcnt(4)"); }
    else if (t + 1 < nT) { asm volatile("s_waitcnt vmcnt(0)"); }
    __builtin_amdgcn_sched_barrier(0);
    __builtin_amdgcn_s_barrier();
  };

  for (int tt = 0; tt < nT; tt += 2) {
    tileK(tt, 0);
    tileK(tt + 1, 1);
  }

#pragma unroll
  for (int mh = 0; mh < 2; ++mh)
#pragma unroll
    for (int m = 0; m < 4; ++m) {
      int row0 = bm * 256 + wr * 128 + mh * 64 + m * 16 + g * 4;
#pragma unroll
      for (int nh = 0; nh < 2; ++nh)
#pragma unroll
        for (int n = 0; n < 2; ++n) {
          int col = bn * 256 + wc * 64 + nh * 32 + n * 16 + l15;
          f32x4 v = acc[mh * 4 + m][nh * 2 + n];
#pragma unroll
          for (int r = 0; r < 4; ++r)
            C[(size_t)(row0 + r) * N + col] = (OutT)v[r];
        }
    }
}

// ---------- merged K-RoPE + V-transpose ----------
// blocks [0,2048): rope_k; blocks [2048,4096): vtrans
__global__ void kvprep_k(const bf16* __restrict__ qkv, const float2* __restrict__ tab,
                         bf16* __restrict__ kout, bf16* __restrict__ vt) {
  if (blockIdx.x < 2048) {
    int idx = blockIdx.x * 256 + threadIdx.x;  // B*S*KVH*16 = 524288
    int c = idx & 15;
    int kvh = (idx >> 4) & 7;
    int s = (idx >> 7) & 2047;
    int b = idx >> 18;
    int d0 = c * 8;
    const bf16* src = qkv + (size_t)(b * 2048 + s) * F_ + kvh * (QPK_ + 2) * D_ + QPK_ * D_ + d0;
    bf16x8 v = *(const bf16x8*)src;
    const float2* tb = tab + s * 64 + (d0 >> 1);
    bf16x8 o;
#pragma unroll
    for (int p = 0; p < 4; ++p) {
      float x0 = (float)v[2 * p], x1 = (float)v[2 * p + 1];
      float2 cs = tb[p];
      o[2 * p]     = (bf16)(x0 * cs.x - x1 * cs.y);
      o[2 * p + 1] = (bf16)(x0 * cs.y + x1 * cs.x);
    }
    *(bf16x8*)(kout + ((size_t)(b * 8 + kvh) * 2048 + s) * 128 + d0) = o;
  } else {
    int bidx = blockIdx.x - 2048;  // B*KVH*4*32 = 2048
    int st = bidx & 31;
    int dt = (bidx >> 5) & 3;
    int kvh = (bidx >> 7) & 7;
    int b = bidx >> 10;
    __shared__ bf16 tile[64][40];
    int t = threadIdx.x;
    {
      int sl = t >> 2, d0 = (t & 3) * 8;
      bf16x8 v = *(const bf16x8*)(qkv + (size_t)(b * 2048 + st * 64 + sl) * F_ +
                                  kvh * (QPK_ + 2) * D_ + (QPK_ + 1) * D_ + dt * 32 + d0);
#pragma unroll
      for (int i = 0; i < 8; ++i) tile[sl][d0 + i] = v[i];
    }
    __syncthreads();
    {
      int dl = t >> 3, s0 = (t & 7) * 8;
      bf16x8 o;
#pragma unroll
      for (int i = 0; i < 8; ++i) o[i] = tile[s0 + i][dl];
      *(bf16x8*)(vt + ((size_t)(b * 8 + kvh) * 128 + dt * 32 + dl) * 2048 + st * 64 + s0) = o;
    }
  }
}

// ---------- causal GQA flash attention (r16: fused Q-RoPE, 2 blocks/CU) ----
__global__ __launch_bounds__(512, 4)
void attn_k(const bf16* __restrict__ qkv, const bf16* __restrict__ k,
            const bf16* __restrict__ vt, const float2* __restrict__ tab,
            bf16* __restrict__ ctx) {
  int bid = blockIdx.x;
  bid = (bid & 7) * 64 + (bid >> 3);   // XCD chunk: each XCD gets 2 (b,kvh) KV sets
  int qp = bid & 7;
  int h = (bid >> 3) & 31;
  int b = bid >> 8;
  int kvh = h >> 2, j = h & 3;
  int tid = threadIdx.x, w = tid >> 6, lane = tid & 63;
  int l15 = lane & 15, g = lane >> 4;

  __shared__ bf16 Ks[2][64 * 128];   // 32KB
  __shared__ bf16 Vs[2][128 * 64];   // 32KB
  __shared__ bf16 Plds[8][16 * 64];  // 16KB, XOR-swizzled rows (128B)

  bf16* Pw = &Plds[w][0];
  const float C2 = 0.08838834764831845f * 1.4426950408889634f;  // scale * log2(e)
  const float NEG = -3.0e38f;

  const bf16* kb_base = k + (size_t)(b * 8 + kvh) * 2048 * 128;
  const bf16* vt_base = vt + (size_t)(b * 8 + kvh) * 128 * 2048;

  auto stage = [&](int kv0, int buf) {
#pragma unroll
    for (int i = 0; i < 2; ++i) {
      int lt = i * 8192 + tid * 16;
      int row = lt >> 8;
      int ch = (lt >> 4) & 15;
      int srcel = (ch ^ (row & 7)) << 3;
      gload16(kb_base + (size_t)(kv0 + row) * 128 + srcel,
              &Ks[buf][(i * 8192 + w * 1024) >> 1]);
    }
#pragma unroll
    for (int i = 0; i < 2; ++i) {
      int lt = i * 8192 + tid * 16;
      int row = lt >> 7;
      int ch = (lt >> 4) & 7;
      int srcel = (ch ^ (row & 7)) << 3;
      gload16(vt_base + (size_t)row * 2048 + kv0 + srcel,
              &Vs[buf][(i * 8192 + w * 1024) >> 1]);
    }
  };

  const int kxor = (l15 & 7) << 4;   // read-side byte swizzle (row = *+l15)

  for (int pass = 0; pass < 2; ++pass) {
    int qt = pass ? (15 - qp) : qp;
    int qrow0 = qt * 128 + w * 16;

    // Q fragments: read from qkv + apply RoPE in-register (lane-local pairs)
    bf16x8 aq[4];
    {
      int s = qrow0 + l15;
      const bf16* qsrc = qkv + (size_t)(b * 2048 + s) * F_ + kvh * (QPK_ + 2) * D_ + j * D_;
      const float2* tb = tab + s * 64;
#pragma unroll
      for (int ks = 0; ks < 4; ++ks) {
        int d0 = ks * 32 + g * 8;
        bf16x8 v = *(const bf16x8*)(qsrc + d0);
        bf16x8 o;
#pragma unroll
        for (int p = 0; p < 4; ++p) {
          float x0 = (float)v[2 * p], x1 = (float)v[2 * p + 1];
          float2 cs = tb[(d0 >> 1) + p];
          o[2 * p]     = (bf16)(x0 * cs.x - x1 * cs.y);
          o[2 * p + 1] = (bf16)(x0 * cs.y + x1 * cs.x);
        }
        aq[ks] = o;
      }
    }

    f32x4 acco[8];
#pragma unroll
    for (int n = 0; n < 8; ++n) acco[n] = (f32x4){0.f, 0.f, 0.f, 0.f};
    float l_r[4] = {0.f, 0.f, 0.f, 0.f};   // per-lane partial denominators

    const int nk = 2 * qt + 2;
    stage(0, 0);
    asm volatile("s_waitcnt vmcnt(0)");
    __builtin_amdgcn_sched_barrier(0);
    __builtin_amdgcn_s_barrier();

    for (int kt = 0; kt < nk; ++kt) {
      int kv0 = kt * 64;
      int cur = kt & 1;
      if (kt + 1 < nk) stage(kv0 + 64, cur ^ 1);   // issue early, lands under compute

      if (kv0 <= qrow0 + 15) {
        f32x4 s[4];
#pragma unroll
        for (int n = 0; n < 4; ++n) s[n] = (f32x4){0.f, 0.f, 0.f, 0.f};
#pragma unroll
        for (int ks = 0; ks < 4; ++ks) {
          int off = ((ks * 64 + g * 16) ^ kxor) >> 1;
#pragma unroll
          for (int n = 0; n < 4; ++n) {
            bf16x8 kb = *(const bf16x8*)&Ks[cur][(n * 16 + l15) * 128 + off];
            s[n] = __builtin_amdgcn_mfma_f32_16x16x32_bf16(aq[ks], kb, s[n], 0, 0, 0);
          }
        }
        if (kv0 + 63 > qrow0) {  // diagonal tile: causal mask
#pragma unroll
          for (int n = 0; n < 4; ++n)
#pragma unroll
            for (int r = 0; r < 4; ++r) {
              int qg = qrow0 + g * 4 + r;
              int kg = kv0 + n * 16 + l15;
              if (kg > qg) s[n][r] = NEG;
            }
        }
        // static-max softmax: P = exp2(s*C2); masked -> exactly 0
#pragma unroll
        for (int n = 0; n < 4; ++n)
#pragma unroll
          for (int r = 0; r < 4; ++r) {
            float p = exp2f(s[n][r] * C2);
            l_r[r] += p;
            int row = g * 4 + r;
            Pw[row * 64 + ((n * 16 + l15) ^ ((row & 7) << 3))] = (bf16)p;
          }
        // P writes -> P reads (wave-local): fence both sides, clobber-free
        __builtin_amdgcn_sched_barrier(0);
        asm volatile("s_waitcnt lgkmcnt(0)");
        __builtin_amdgcn_sched_barrier(0);
#pragma unroll
        for (int ks = 0; ks < 2; ++ks) {
          bf16x8 pa = *(const bf16x8*)&Pw[l15 * 64 + (((ks * 64 + g * 16) ^ kxor) >> 1)];
          int off = ((ks * 64 + g * 16) ^ kxor) >> 1;
#pragma unroll
          for (int n = 0; n < 8; ++n) {
            bf16x8 vb = *(const bf16x8*)&Vs[cur][(n * 16 + l15) * 64 + off];
            acco[n] = __builtin_amdgcn_mfma_f32_16x16x32_bf16(pa, vb, acco[n], 0, 0, 0);
          }
        }
      }

      if (kt + 1 < nk) { asm volatile("s_waitcnt vmcnt(0)"); }
      __builtin_amdgcn_sched_barrier(0);
      __builtin_amdgcn_s_barrier();
    }

    // epilogue: ONE denominator reduce per pass, then normalize and store
#pragma unroll
    for (int r = 0; r < 4; ++r) {
      float ps = l_r[r];
#pragma unroll
      for (int off = 1; off < 16; off <<= 1) ps += __shfl_xor(ps, off);
      float inv = 1.0f / ps;
      int qg = qrow0 + g * 4 + r;
#pragma unroll
      for (int n = 0; n < 8; ++n)
        ctx[(((size_t)b * 2048 + qg) * 32 + h) * 128 + n * 16 + l15] = (bf16)(acco[n][r] * inv);
    }
    __builtin_amdgcn_s_barrier();   // pass boundary before re-staging buf 0
  }
}

// ---------- launcher ----------
extern "C" void kernel_launch(void* const* d_in, const int* in_sizes, int n_in,
                              void* d_out, int out_size, void* d_ws, size_t ws_size,
                              hipStream_t stream) {
  const float* x = (const float*)d_in[0];
  const float* wqkv = (const float*)d_in[1];
  const float* wo = (const float*)d_in[2];
  float* out = (float*)d_out;
  char* ws = (char*)d_ws;

  // workspace layout (bytes); total = 185,597,952
  bf16* xbf    = (bf16*)(ws + 0);            // 33,554,432  (reused as ctx later)
  bf16* wqkvbf = (bf16*)(ws + 33554432);     // 50,331,648
  bf16* qkvbf  = (bf16*)(ws + 83886080);     // 50,331,648  (LIVE until attn done)
  bf16* wobf   = (bf16*)(ws + 134217728);    // 33,554,432
  bf16* kbuf   = (bf16*)(ws + 167772160);    // 8,388,608
  bf16* vtbuf  = (bf16*)(ws + 176160768);    // 8,388,608
  float2* tab  = (float2*)(ws + 184549376);  // 1,048,576

  // 1. merged converts (x, wqkv, wo) + rope table (one launch)
  init_k<<<29184, 256, 0, stream>>>(x, xbf, wqkv, wqkvbf, wo, wobf, tab);

  // 2. QKV projection: 256x192 tiles -> 16x32 = 512 blocks = 2 exact rounds
  gemm192<bf16><<<dim3(M_ / 256, F_ / 192), 512, 0, stream>>>(xbf, wqkvbf, qkvbf, M_, F_, E_);

  // 3. merged K-RoPE + V-transpose (one launch)
  kvprep_k<<<4096, 256, 0, stream>>>(qkvbf, tab, kbuf, vtbuf);

  // 4. attention (Q from qkv + fused RoPE) -> ctx (xbf region, dead after GEMM1)
  bf16* ctx = xbf;
  attn_k<<<512, 512, 0, stream>>>(qkvbf, kbuf, vtbuf, tab, ctx);

  // 5. output projection: 256x256 tiles -> 16x16 = 256 blocks = 1 exact round
  gemm256<float><<<dim3(M_ / 256, E_ / 256), 512, 0, stream>>>(ctx, wobf, out, M_, E_, E_);
}